// Round 4
// baseline (53.005 us; speedup 1.0000x reference)
//
#include <hip/hip_runtime.h>

// Camera ISP fused: mosaic -> 3x3 gauss blur -> 17-knot LUT -> +noise ->
// sparse 5x5 demosaic -> bayer-parity select -> clip.
// Round 3: drop s_bayer LDS stage (direct global plane reads in stage B),
// single noisy LDS buffer (11.3 KB) -> 8 blocks/CU, one less barrier phase.

#define TX 64
#define TY 32
#define NROWS 36       // noisy rows: gy0-2 .. gy0+33
#define NSTRIDE 76     // 76%32=12 -> conflict-free stage C

typedef float f4u __attribute__((ext_vector_type(4), aligned(4)));

__device__ __forceinline__ int refl(int i, int n) {
    return i < 0 ? -i : (i >= n ? 2 * n - 2 - i : i);
}

__device__ __forceinline__ float clip01(float x) {
    return fminf(fmaxf(x * (1.0f / 255.0f), 0.0f), 1.0f);
}

__global__ __launch_bounds__(256, 8) void camera_kernel(
    const float* __restrict__ im, const float* __restrict__ yp,
    const float* __restrict__ noise, float* __restrict__ out,
    int H, int W)
{
    __shared__ float s_noisy[NROWS * NSTRIDE];   // 10944 B
    __shared__ float2 s_tab[3][16];              // 384 B

    const int b   = blockIdx.z;
    const int gy0 = blockIdx.y * TY;   // even
    const int gx0 = blockIdx.x * TX;   // even
    const int tid = threadIdx.x;

    if (tid < 48) {
        int ch = tid >> 4, i = tid & 15;
        s_tab[ch][i] = make_float2(yp[ch * 17 + i], yp[ch * 17 + i + 1]);
    }
    __syncthreads();

    const size_t HW = (size_t)H * W;
    const float* p0 = im + (size_t)b * 3 * HW;         // ch0
    const float* p1 = p0 + HW;                          // ch1
    const float* p2 = p1 + HW;                          // ch2
    const float* nzb = noise + (size_t)b * HW;

    const float g0 = 0.04038794f;   // 1D gauss tail (sigma=0.4, normalized)
    const float g1 = 0.91922413f;   // 1D gauss center

    // ---- Stage B: noisy row-pairs = interp(blur(mosaic)) + noise ----
    // mosaic values are NOT pre-scaled by 255; fold 255*(16/255)=16 into interp.
    for (int idx = tid; idx < 18 * 18; idx += 256) {
        int rp = idx / 18, c4 = idx - rp * 18;
        int py0 = gy0 - 2 + 2 * rp;               // even output row of the pair
        int x0  = gx0 - 4 + 4 * c4;               // first output col (even)
        int ya = refl(py0 - 1, H);                // odd row
        int yb = refl(py0,     H);                // even row
        int yc = refl(py0 + 1, H);                // odd row
        int yd = refl(py0 + 2, H);                // even row

        // vertical blur accumulators, cols x0-1 .. x0+4
        float t0[6], t1[6];
        if (x0 >= 1 && x0 <= W - 5) {
            // fast path: unaligned vector loads, col x0-1+j; j even = odd col.
            // odd rows: odd col->ch1, even col->ch0; even rows: ch2/ch1.
            #define LDMOS(podd, peven, yy, m)                                 \
                {                                                             \
                    const float* pa = (podd)  + (size_t)(yy) * W;             \
                    const float* pb = (peven) + (size_t)(yy) * W;             \
                    f4u alo = *(const f4u*)(pa + x0 - 1);                     \
                    f4u ahi = *(const f4u*)(pa + x0 + 1);                     \
                    f4u blo = *(const f4u*)(pb + x0 - 1);                     \
                    f4u bhi = *(const f4u*)(pb + x0 + 1);                     \
                    m[0] = alo.x; m[1] = blo.y; m[2] = alo.z;                 \
                    m[3] = blo.w; m[4] = ahi.z; m[5] = bhi.w;                 \
                }
            float m[6];
            LDMOS(p1, p0, ya, m);                 // row ya (odd)
            #pragma unroll
            for (int j = 0; j < 6; ++j) t0[j] = g0 * m[j];
            LDMOS(p2, p1, yb, m);                 // row yb (even)
            #pragma unroll
            for (int j = 0; j < 6; ++j) { t0[j] = fmaf(g1, m[j], t0[j]); t1[j] = g0 * m[j]; }
            LDMOS(p1, p0, yc, m);                 // row yc (odd)
            #pragma unroll
            for (int j = 0; j < 6; ++j) { t0[j] = fmaf(g0, m[j], t0[j]); t1[j] = fmaf(g1, m[j], t1[j]); }
            LDMOS(p2, p1, yd, m);                 // row yd (even)
            #pragma unroll
            for (int j = 0; j < 6; ++j) t1[j] = fmaf(g0, m[j], t1[j]);
            #undef LDMOS
        } else {
            #pragma unroll
            for (int j = 0; j < 6; ++j) {
                int xx = refl(x0 - 1 + j, W);     // parity preserved
                bool oddc = (xx & 1) != 0;
                size_t oa = (size_t)ya * W + xx, ob = (size_t)yb * W + xx;
                size_t oc = (size_t)yc * W + xx, od = (size_t)yd * W + xx;
                float a  = oddc ? p1[oa] : p0[oa];
                float bq = oddc ? p2[ob] : p1[ob];
                float cq = oddc ? p1[oc] : p0[oc];
                float dq = oddc ? p2[od] : p1[od];
                t0[j] = fmaf(g0, a + cq,  g1 * bq);
                t1[j] = fmaf(g0, bq + dq, g1 * cq);
            }
        }

        // noise loads
        float4 nz0, nz1;
        if (x0 >= 0 && x0 + 3 < W) {
            nz0 = *(const float4*)(nzb + (size_t)yb * W + x0);
            nz1 = *(const float4*)(nzb + (size_t)yc * W + x0);
        } else {
            const float* n0 = nzb + (size_t)yb * W;
            const float* n1 = nzb + (size_t)yc * W;
            int xa = refl(x0, W), xb2 = refl(x0 + 1, W),
                xc2 = refl(x0 + 2, W), xd2 = refl(x0 + 3, W);
            nz0 = make_float4(n0[xa], n0[xb2], n0[xc2], n0[xd2]);
            nz1 = make_float4(n1[xa], n1[xb2], n1[xc2], n1[xd2]);
        }

        // horizontal blur + LUT interp (+16 fold) + noise
        float o0[4], o1[4];
        #pragma unroll
        for (int i = 0; i < 4; ++i) {
            float s0 = fmaf(g0, t0[i] + t0[i + 2], g1 * t0[i + 1]) * 16.0f;
            float s1 = fmaf(g0, t1[i] + t1[i + 2], g1 * t1[i + 1]) * 16.0f;
            int i0 = (int)s0; i0 = i0 > 15 ? 15 : (i0 < 0 ? 0 : i0);
            int i1 = (int)s1; i1 = i1 > 15 ? 15 : (i1 < 0 ? 0 : i1);
            float2 pa = s_tab[(i & 1) ? 2 : 1][i0];   // even row: ch1/ch2
            float2 pb = s_tab[(i & 1) ? 1 : 0][i1];   // odd row:  ch0/ch1
            o0[i] = fmaf(s0 - (float)i0, pa.y - pa.x, pa.x);
            o1[i] = fmaf(s1 - (float)i1, pb.y - pb.x, pb.x);
        }
        *(float4*)&s_noisy[(2 * rp) * NSTRIDE + 4 * c4] =
            make_float4(o0[0] + nz0.x, o0[1] + nz0.y, o0[2] + nz0.z, o0[3] + nz0.w);
        *(float4*)&s_noisy[(2 * rp + 1) * NSTRIDE + 4 * c4] =
            make_float4(o1[0] + nz1.x, o1[1] + nz1.y, o1[2] + nz1.z, o1[3] + nz1.w);
    }
    __syncthreads();

    // ---- Stage C: demosaic, 2 output rows x 4 cols per thread ----
    const int rp = tid >> 4;      // 0..15
    const int c4 = tid & 15;      // 0..15
    const int nbase = (2 * rp + 2) * NSTRIDE + 4 * c4;
    float w[4][12];               // noisy rows 2rp+1 .. 2rp+4, cols idx 4c4..+11
    #pragma unroll
    for (int rr = 0; rr < 4; ++rr) {
        const float* p = &s_noisy[nbase + (rr - 1) * NSTRIDE];
        *(float4*)&w[rr][0] = *(const float4*)(p);
        *(float4*)&w[rr][4] = *(const float4*)(p + 4);
        *(float4*)&w[rr][8] = *(const float4*)(p + 8);
    }
    float4 c2u = *(const float4*)&s_noisy[nbase - 2 * NSTRIDE + 4];  // row 2rp centers
    float4 c2d = *(const float4*)&s_noisy[nbase + 3 * NSTRIDE + 4];  // row 2rp+5 centers
    float cu[4] = {c2u.x, c2u.y, c2u.z, c2u.w};
    float cd[4] = {c2d.x, c2d.y, c2d.z, c2d.w};

    float R0[4], G0[4], B0[4], R1[4], G1[4], B1[4];

    auto dem = [&](const float (&up)[12], const float (&ct)[12], const float (&dn)[12],
                   const float* u2, const float* d2, bool rowOdd,
                   float* R, float* G, float* Bv) {
        #pragma unroll
        for (int i = 0; i < 4; ++i) {
            float c    = ct[4 + i];
            float ax1x = ct[3 + i] + ct[5 + i];
            float ax2x = ct[2 + i] + ct[6 + i];
            float ax1y = up[4 + i] + dn[4 + i];
            float diag = up[3 + i] + up[5 + i] + dn[3 + i] + dn[5 + i];
            float ax2y = u2[i] + d2[i];
            const bool xOdd = (i & 1) != 0;
            if (!xOdd && !rowOdd) {          // p00: R=v, G=raw, B=h
                float h = (0.5f * ax2y - diag - ax2x + 4.0f * ax1x + 5.0f * c) * 0.125f;
                float v = (0.5f * ax2x - diag - ax2y + 4.0f * ax1y + 5.0f * c) * 0.125f;
                R[i] = v; G[i] = c; Bv[i] = h;
            } else if (xOdd && !rowOdd) {    // p01: R=d, G=g, B=raw
                float g = (2.0f * (ax1y + ax1x) - ax2y - ax2x + 4.0f * c) * 0.125f;
                float d = (2.0f * diag - 1.5f * (ax2y + ax2x) + 6.0f * c) * 0.125f;
                R[i] = d; G[i] = g; Bv[i] = c;
            } else if (!xOdd && rowOdd) {    // p10: R=raw, G=g, B=d
                float g = (2.0f * (ax1y + ax1x) - ax2y - ax2x + 4.0f * c) * 0.125f;
                float d = (2.0f * diag - 1.5f * (ax2y + ax2x) + 6.0f * c) * 0.125f;
                R[i] = c; G[i] = g; Bv[i] = d;
            } else {                         // p11: R=h, G=raw, B=v
                float h = (0.5f * ax2y - diag - ax2x + 4.0f * ax1x + 5.0f * c) * 0.125f;
                float v = (0.5f * ax2x - diag - ax2y + 4.0f * ax1y + 5.0f * c) * 0.125f;
                R[i] = h; G[i] = c; Bv[i] = v;
            }
        }
    };

    dem(w[0], w[1], w[2], cu,       &w[3][4], false, R0, G0, B0);  // even row
    dem(w[1], w[2], w[3], &w[0][4], cd,       true,  R1, G1, B1);  // odd row

    const size_t outb = (size_t)b * 3 * HW;
    int py = gy0 + 2 * rp;
    size_t o = outb + (size_t)py * W + (gx0 + 4 * c4);
    *(float4*)(out + o) = make_float4(clip01(R0[0]), clip01(R0[1]), clip01(R0[2]), clip01(R0[3]));
    *(float4*)(out + o + HW) = make_float4(clip01(G0[0]), clip01(G0[1]), clip01(G0[2]), clip01(G0[3]));
    *(float4*)(out + o + 2 * HW) = make_float4(clip01(B0[0]), clip01(B0[1]), clip01(B0[2]), clip01(B0[3]));
    o += W;
    *(float4*)(out + o) = make_float4(clip01(R1[0]), clip01(R1[1]), clip01(R1[2]), clip01(R1[3]));
    *(float4*)(out + o + HW) = make_float4(clip01(G1[0]), clip01(G1[1]), clip01(G1[2]), clip01(G1[3]));
    *(float4*)(out + o + 2 * HW) = make_float4(clip01(B1[0]), clip01(B1[1]), clip01(B1[2]), clip01(B1[3]));
}

extern "C" void kernel_launch(void* const* d_in, const int* in_sizes, int n_in,
                              void* d_out, int out_size, void* d_ws, size_t ws_size,
                              hipStream_t stream) {
    const float* im    = (const float*)d_in[0];
    const float* yp    = (const float*)d_in[1];
    const float* noise = (const float*)d_in[2];
    float* out = (float*)d_out;

    const int H = 512, W = 512;
    const int B = in_sizes[2] / (H * W);   // noise is (B,1,H,W)

    dim3 grid(W / TX, H / TY, B);
    camera_kernel<<<grid, 256, 0, stream>>>(im, yp, noise, out, H, W);
}

// Round 5
// 51.056 us; speedup vs baseline: 1.0382x; 1.0382x over previous
//
#include <hip/hip_runtime.h>

// Camera ISP fused: mosaic -> 3x3 gauss blur -> 17-knot LUT -> +noise ->
// sparse 5x5 demosaic -> bayer-parity select -> clip.
// Round 4: R2 structure (LDS bayer + LDS noisy, strides 84/76) but ALL global
// loads (mosaic + noise) hoisted into one top-of-kernel prefetch burst into
// registers -> continuous VMEM in flight; noise consumed from regs in stage B.

#define TX 64
#define TY 32
#define BROWS 38       // bayer rows: gy0-3 .. gy0+34
#define BSTR  84       // floats; 84%32=20
#define NROWS 36       // noisy rows: gy0-2 .. gy0+33
#define NSTR  76       // 76%32=12 -> conflict-free stage C

typedef float f4u __attribute__((ext_vector_type(4), aligned(4)));

__device__ __forceinline__ int refl(int i, int n) {
    return i < 0 ? -i : (i >= n ? 2 * n - 2 - i : i);
}

__device__ __forceinline__ float clip01(float x) {
    return fminf(fmaxf(x * (1.0f / 255.0f), 0.0f), 1.0f);
}

__global__ __launch_bounds__(256, 5) void camera_kernel(
    const float* __restrict__ im, const float* __restrict__ yp,
    const float* __restrict__ noise, float* __restrict__ out,
    int H, int W)
{
    __shared__ float s_bayer[BROWS * BSTR];   // 12768 B
    __shared__ float s_noisy[NROWS * NSTR];   // 10944 B
    __shared__ float2 s_tab[3][16];           // 384 B

    const int b   = blockIdx.z;
    const int gy0 = blockIdx.y * TY;   // even
    const int gx0 = blockIdx.x * TX;   // even
    const int tid = threadIdx.x;

    const size_t HW = (size_t)H * W;
    const float* imb = im + (size_t)b * 3 * HW;
    const float* nzb = noise + (size_t)b * HW;

    // ================= PREFETCH BURST: all global loads =================
    // Mosaic slots (stage A): 760 float4-sites, 3 grid-stride slots.
    f4u va[3], vb[3];
    #pragma unroll
    for (int s = 0; s < 3; ++s) {
        int idx = tid + 256 * s;
        if (idx < BROWS * 20) {
            int r = idx / 20, j = idx - r * 20;
            int py = gy0 + r - 3;
            int y  = refl(py, H);                 // parity-preserving
            int px4 = gx0 - 8 + 4 * j;
            int chLo = (py & 1) ? 0 : 1;          // CMAP[[1,2],[0,1]]
            const float* pl = imb + (size_t)chLo * HW + (size_t)y * W;
            const float* ph = pl + HW;
            if (px4 >= 0 && px4 + 3 < W) {
                va[s] = *(const f4u*)(pl + px4);
                vb[s] = *(const f4u*)(ph + px4);
            } else {
                int x0 = refl(px4 + 0, W); float t0 = ((px4 + 0) & 1) ? ph[x0] : pl[x0];
                int x1 = refl(px4 + 1, W); float t1 = ((px4 + 1) & 1) ? ph[x1] : pl[x1];
                int x2 = refl(px4 + 2, W); float t2 = ((px4 + 2) & 1) ? ph[x2] : pl[x2];
                int x3 = refl(px4 + 3, W); float t3 = ((px4 + 3) & 1) ? ph[x3] : pl[x3];
                f4u m; m.x = t0; m.y = t1; m.z = t2; m.w = t3;
                va[s] = m; vb[s] = m;             // already merged
            }
        }
    }
    // Noise slots (stage B): 324 sites, 2 grid-stride slots, 2 rows each.
    f4u nz0[2], nz1[2];
    #pragma unroll
    for (int s = 0; s < 2; ++s) {
        int idx = tid + 256 * s;
        if (idx < 18 * 18) {
            int rp = idx / 18, c4 = idx - rp * 18;
            int py0 = gy0 - 2 + 2 * rp;
            int yb = refl(py0, H), yc = refl(py0 + 1, H);
            int x0 = gx0 - 4 + 4 * c4;
            if (x0 >= 0 && x0 + 3 < W) {
                nz0[s] = *(const f4u*)(nzb + (size_t)yb * W + x0);
                nz1[s] = *(const f4u*)(nzb + (size_t)yc * W + x0);
            } else {
                const float* n0 = nzb + (size_t)yb * W;
                const float* n1 = nzb + (size_t)yc * W;
                int xa = refl(x0, W), xb2 = refl(x0 + 1, W),
                    xc2 = refl(x0 + 2, W), xd2 = refl(x0 + 3, W);
                f4u u; u.x = n0[xa]; u.y = n0[xb2]; u.z = n0[xc2]; u.w = n0[xd2];
                f4u v; v.x = n1[xa]; v.y = n1[xb2]; v.z = n1[xc2]; v.w = n1[xd2];
                nz0[s] = u; nz1[s] = v;
            }
        }
    }
    // LUT pairs
    if (tid < 48) {
        int ch = tid >> 4, i = tid & 15;
        s_tab[ch][i] = make_float2(yp[ch * 17 + i], yp[ch * 17 + i + 1]);
    }

    // ---- Stage A: parity-merge and stash bayer tile in LDS (unscaled) ----
    #pragma unroll
    for (int s = 0; s < 3; ++s) {
        int idx = tid + 256 * s;
        if (idx < BROWS * 20) {
            int r = idx / 20, j = idx - r * 20;
            f4u m; m.x = va[s].x; m.y = vb[s].y; m.z = va[s].z; m.w = vb[s].w;
            *(f4u*)&s_bayer[r * BSTR + 4 * j] = m;
        }
    }
    __syncthreads();

    // ---- Stage B: noisy row-pairs = interp(blur(bayer)) + noise(regs) ----
    const float g0 = 0.04038794f;   // 1D gauss tail (sigma=0.4, normalized)
    const float g1 = 0.91922413f;   // 1D gauss center
    #pragma unroll
    for (int s = 0; s < 2; ++s) {
        int idx = tid + 256 * s;
        if (idx < 18 * 18) {
            int rp = idx / 18, c4 = idx - rp * 18;
            const float* rb = &s_bayer[(2 * rp) * BSTR + 4 * c4];
            float q[4][12];
            #pragma unroll
            for (int rr = 0; rr < 4; ++rr) {
                const float* p = rb + rr * BSTR;
                *(f4u*)&q[rr][0] = *(const f4u*)(p);
                *(f4u*)&q[rr][4] = *(const f4u*)(p + 4);
                *(f4u*)&q[rr][8] = *(const f4u*)(p + 8);
            }
            float t0[6], t1[6];
            #pragma unroll
            for (int k = 0; k < 6; ++k) {
                float a = q[0][3 + k], bb = q[1][3 + k];
                float c = q[2][3 + k], d = q[3][3 + k];
                t0[k] = fmaf(g0, a + c,  g1 * bb);   // vblur row py0 (even)
                t1[k] = fmaf(g0, bb + d, g1 * c);    // vblur row py0+1 (odd)
            }
            float o0[4], o1[4];
            #pragma unroll
            for (int i = 0; i < 4; ++i) {
                float s0 = fmaf(g0, t0[i] + t0[i + 2], g1 * t0[i + 1]) * 16.0f;
                float s1 = fmaf(g0, t1[i] + t1[i + 2], g1 * t1[i + 1]) * 16.0f;
                int i0 = (int)s0; i0 = i0 > 15 ? 15 : (i0 < 0 ? 0 : i0);
                int i1 = (int)s1; i1 = i1 > 15 ? 15 : (i1 < 0 ? 0 : i1);
                float2 pa = s_tab[(i & 1) ? 2 : 1][i0];   // even row: ch1/ch2
                float2 pb = s_tab[(i & 1) ? 1 : 0][i1];   // odd row:  ch0/ch1
                o0[i] = fmaf(s0 - (float)i0, pa.y - pa.x, pa.x);
                o1[i] = fmaf(s1 - (float)i1, pb.y - pb.x, pb.x);
            }
            f4u w0; w0.x = o0[0] + nz0[s].x; w0.y = o0[1] + nz0[s].y;
                    w0.z = o0[2] + nz0[s].z; w0.w = o0[3] + nz0[s].w;
            f4u w1; w1.x = o1[0] + nz1[s].x; w1.y = o1[1] + nz1[s].y;
                    w1.z = o1[2] + nz1[s].z; w1.w = o1[3] + nz1[s].w;
            *(f4u*)&s_noisy[(2 * rp) * NSTR + 4 * c4] = w0;
            *(f4u*)&s_noisy[(2 * rp + 1) * NSTR + 4 * c4] = w1;
        }
    }
    __syncthreads();

    // ---- Stage C: demosaic, 2 output rows x 4 cols per thread ----
    const int rp = tid >> 4;      // 0..15
    const int c4 = tid & 15;      // 0..15
    const int nbase = (2 * rp + 2) * NSTR + 4 * c4;
    float w[4][12];               // noisy rows 2rp+1 .. 2rp+4
    #pragma unroll
    for (int rr = 0; rr < 4; ++rr) {
        const float* p = &s_noisy[nbase + (rr - 1) * NSTR];
        *(f4u*)&w[rr][0] = *(const f4u*)(p);
        *(f4u*)&w[rr][4] = *(const f4u*)(p + 4);
        *(f4u*)&w[rr][8] = *(const f4u*)(p + 8);
    }
    f4u c2u = *(const f4u*)&s_noisy[nbase - 2 * NSTR + 4];  // row 2rp centers
    f4u c2d = *(const f4u*)&s_noisy[nbase + 3 * NSTR + 4];  // row 2rp+5 centers
    float cu[4] = {c2u.x, c2u.y, c2u.z, c2u.w};
    float cd[4] = {c2d.x, c2d.y, c2d.z, c2d.w};

    float R0[4], G0[4], B0[4], R1[4], G1[4], B1[4];

    auto dem = [&](const float (&up)[12], const float (&ct)[12], const float (&dn)[12],
                   const float* u2, const float* d2, bool rowOdd,
                   float* R, float* G, float* Bv) {
        #pragma unroll
        for (int i = 0; i < 4; ++i) {
            float c    = ct[4 + i];
            float ax1x = ct[3 + i] + ct[5 + i];
            float ax2x = ct[2 + i] + ct[6 + i];
            float ax1y = up[4 + i] + dn[4 + i];
            float diag = up[3 + i] + up[5 + i] + dn[3 + i] + dn[5 + i];
            float ax2y = u2[i] + d2[i];
            const bool xOdd = (i & 1) != 0;
            if (!xOdd && !rowOdd) {          // p00: R=v, G=raw, B=h
                float h = (0.5f * ax2y - diag - ax2x + 4.0f * ax1x + 5.0f * c) * 0.125f;
                float v = (0.5f * ax2x - diag - ax2y + 4.0f * ax1y + 5.0f * c) * 0.125f;
                R[i] = v; G[i] = c; Bv[i] = h;
            } else if (xOdd && !rowOdd) {    // p01: R=d, G=g, B=raw
                float g = (2.0f * (ax1y + ax1x) - ax2y - ax2x + 4.0f * c) * 0.125f;
                float d = (2.0f * diag - 1.5f * (ax2y + ax2x) + 6.0f * c) * 0.125f;
                R[i] = d; G[i] = g; Bv[i] = c;
            } else if (!xOdd && rowOdd) {    // p10: R=raw, G=g, B=d
                float g = (2.0f * (ax1y + ax1x) - ax2y - ax2x + 4.0f * c) * 0.125f;
                float d = (2.0f * diag - 1.5f * (ax2y + ax2x) + 6.0f * c) * 0.125f;
                R[i] = c; G[i] = g; Bv[i] = d;
            } else {                         // p11: R=h, G=raw, B=v
                float h = (0.5f * ax2y - diag - ax2x + 4.0f * ax1x + 5.0f * c) * 0.125f;
                float v = (0.5f * ax2x - diag - ax2y + 4.0f * ax1y + 5.0f * c) * 0.125f;
                R[i] = h; G[i] = c; Bv[i] = v;
            }
        }
    };

    dem(w[0], w[1], w[2], cu,       &w[3][4], false, R0, G0, B0);  // even row
    dem(w[1], w[2], w[3], &w[0][4], cd,       true,  R1, G1, B1);  // odd row

    const size_t outb = (size_t)b * 3 * HW;
    int py = gy0 + 2 * rp;
    size_t o = outb + (size_t)py * W + (gx0 + 4 * c4);
    *(float4*)(out + o) = make_float4(clip01(R0[0]), clip01(R0[1]), clip01(R0[2]), clip01(R0[3]));
    *(float4*)(out + o + HW) = make_float4(clip01(G0[0]), clip01(G0[1]), clip01(G0[2]), clip01(G0[3]));
    *(float4*)(out + o + 2 * HW) = make_float4(clip01(B0[0]), clip01(B0[1]), clip01(B0[2]), clip01(B0[3]));
    o += W;
    *(float4*)(out + o) = make_float4(clip01(R1[0]), clip01(R1[1]), clip01(R1[2]), clip01(R1[3]));
    *(float4*)(out + o + HW) = make_float4(clip01(G1[0]), clip01(G1[1]), clip01(G1[2]), clip01(G1[3]));
    *(float4*)(out + o + 2 * HW) = make_float4(clip01(B1[0]), clip01(B1[1]), clip01(B1[2]), clip01(B1[3]));
}

extern "C" void kernel_launch(void* const* d_in, const int* in_sizes, int n_in,
                              void* d_out, int out_size, void* d_ws, size_t ws_size,
                              hipStream_t stream) {
    const float* im    = (const float*)d_in[0];
    const float* yp    = (const float*)d_in[1];
    const float* noise = (const float*)d_in[2];
    float* out = (float*)d_out;

    const int H = 512, W = 512;
    const int B = in_sizes[2] / (H * W);   // noise is (B,1,H,W)

    dim3 grid(W / TX, H / TY, B);
    camera_kernel<<<grid, 256, 0, stream>>>(im, yp, noise, out, H, W);
}